// Round 1
// baseline (149.906 us; speedup 1.0000x reference)
//
#include <hip/hip_runtime.h>

// Grapher_6356551598738 — the reference graph collapses to:
//   out[n,c,p] = relu( x[n,c,p] + A4[c] )
// where A4[c] = c4[c] + s4[c] * sum_{o=0..127} relu(cn[o]) * w4[c,o].
// Everything upstream (fc1, inter_part_MR, fc2, residual, fc3, and the
// grouped conv input of intra_part_MR) is value-dead: both MR blocks ignore
// their input values (inter uses a constant mask; intra uses zeros_like).
// So this is a single memory-bound elementwise pass: 62.9 MB read + 62.9 MB
// write of fp32.

#define THREADS 256

__global__ __launch_bounds__(THREADS) void grapher_fused(
    const float* __restrict__ x,
    const float* __restrict__ cn,   // (128,)
    const float* __restrict__ w4,   // (64,128) row-major
    const float* __restrict__ s4,   // (64,)
    const float* __restrict__ c4,   // (64,)
    float* __restrict__ out,
    int n4)                          // number of float4 elements
{
    __shared__ float A4[64];
    __shared__ __align__(16) float addv[960];   // addv[c*15+p] = A4[c]

    const int t = threadIdx.x;

    // Per-block recompute of the tiny constant vector (w4/cn L2-resident).
    if (t < 64) {
        float acc = 0.f;
        #pragma unroll 8
        for (int o = 0; o < 128; ++o)
            acc = fmaf(fmaxf(cn[o], 0.f), w4[t * 128 + o], acc);
        A4[t] = fmaf(s4[t], acc, c4[t]);
    }
    __syncthreads();
    for (int j = t; j < 960; j += THREADS)
        addv[j] = A4[j / 15];
    __syncthreads();

    // Grid-stride float4 elementwise: out = relu(x + addv[i % 960]).
    // 960 % 4 == 0, so a float4's 4 lanes never wrap the 960 period and the
    // LDS read stays 16B-aligned.
    const float4* __restrict__ x4 = (const float4*)x;
    float4* __restrict__ o4 = (float4*)out;
    const int stride = gridDim.x * THREADS;
    for (int k = blockIdx.x * THREADS + t; k < n4; k += stride) {
        const int j = (k * 4) % 960;
        const float4 v = x4[k];
        const float4 a = *(const float4*)&addv[j];
        float4 r;
        r.x = fmaxf(v.x + a.x, 0.f);
        r.y = fmaxf(v.y + a.y, 0.f);
        r.z = fmaxf(v.z + a.z, 0.f);
        r.w = fmaxf(v.w + a.w, 0.f);
        o4[k] = r;
    }
}

extern "C" void kernel_launch(void* const* d_in, const int* in_sizes, int n_in,
                              void* d_out, int out_size, void* d_ws, size_t ws_size,
                              hipStream_t stream) {
    // setup_inputs order:
    // 0:x 1:w1 2:s1 3:c1 4:wi 5:si 6:ci 7:w2 8:s2 9:c2
    // 10:w3 11:s3 12:c3 13:wn 14:sn 15:cn 16:w4 17:s4 18:c4
    const float* x  = (const float*)d_in[0];
    const float* cn = (const float*)d_in[15];
    const float* w4 = (const float*)d_in[16];
    const float* s4 = (const float*)d_in[17];
    const float* c4 = (const float*)d_in[18];
    float* out = (float*)d_out;

    const int n4 = out_size / 4;          // 15,728,640 / 4 = 3,932,160
    const int blocks = 2048;              // 256 CU x 8 blocks, grid-stride
    grapher_fused<<<blocks, THREADS, 0, stream>>>(x, cn, w4, s4, c4, out, n4);
}